// Round 8
// baseline (124.691 us; speedup 1.0000x reference)
//
#include <hip/hip_runtime.h>
#include <math.h>

#define IMG 416
#define N_ANG 320
#define N_DET 416
#define N_SAMP 416

// ---------------------------------------------------------------------------
// Global quad table Gq: quad(pr,pc) for pr,pc in [-2,417], stride 424 words.
// Gq[(pr+2)*424 + (pc+2)] = fp8 e4m3 x4 {v(pr,pc), v(pr,pc+1), v(pr+1,pc),
// v(pr+1,pc+1)} of the zero-padded diff image (bytes 0..3 of one uint).
// ---------------------------------------------------------------------------
#define GQSTRIDE 424
#define GQROWS   420
#define GQWORDS  (GQROWS * GQSTRIDE)      // 178080 words
#define GQBYTES  ((size_t)GQWORDS * 4)    // 712320 B

#define SPLANE  (N_ANG * N_DET)           // 133120 rays
#define SBYTES  ((size_t)SPLANE * 4)
#define WSNEED  (GQBYTES + SBYTES)        // ~1.25 MB

// LDS tile: 108 rows x 108 words staged at stride 116 words (= 464 B).
// 116 % 32 = 20 -> 8-row bank-residue cycle => near-conflict-free reads for
// any ray-front orientation; 116 % 4 == 0 keeps rows 16B-aligned for b128.
#define LSTRIDE 116
#define LWORDS  (108 * LSTRIDE)           // 12528 words = 50112 B -> 3 blk/CU

typedef float vfloat2 __attribute__((ext_vector_type(2)));

// ---------------------------------------------------------------------------
// Kernel A: build the quad table; zero the sinogram plane S and d_out.
// ---------------------------------------------------------------------------
__global__ __launch_bounds__(256) void pack_kernel(const float* __restrict__ a,
                                                   const float* __restrict__ b,
                                                   unsigned int* __restrict__ Gq,
                                                   float* __restrict__ S,
                                                   float* __restrict__ out) {
    int i = blockIdx.x * 256 + threadIdx.x;
    if (i == 0) out[0] = 0.0f;
    if (i < SPLANE) S[i] = 0.0f;
    if (i >= GQWORDS) return;
    int row  = i / GQSTRIDE;
    int colw = i - row * GQSTRIDE;
    int pr = row - 2, pc = colw - 2;
    auto D = [&](int r, int c) -> float {
        if ((unsigned)r < (unsigned)IMG && (unsigned)c < (unsigned)IMG) {
            int idx = r * IMG + c;
            return a[idx] - b[idx];
        }
        return 0.0f;
    };
    const float v00 = D(pr, pc),     v01 = D(pr, pc + 1);
    const float v10 = D(pr + 1, pc), v11 = D(pr + 1, pc + 1);
    unsigned int u = __builtin_amdgcn_cvt_pk_fp8_f32(v00, v01, 0u, false);
    u = __builtin_amdgcn_cvt_pk_fp8_f32(v10, v11, u, true);
    Gq[i] = u;
}

__global__ void zero_out_kernel(float* __restrict__ out) {
    if (threadIdx.x == 0) out[0] = 0.0f;
}

// ---------------------------------------------------------------------------
// Kernel B: block = (angle, 1-of-16 104x104 tile). Stage the tile's quads
// into LDS via dwordx4, then thread d marches its ray's exact sample range
// inside the tile box (half-open -> each sample owned by exactly one tile).
// One ds_read_b32 + 2 HW fp8 unpacks per bilinear sample. Partial ray sums
// atomicAdd into S (<=4 adds per ray).
// ---------------------------------------------------------------------------
__global__ __launch_bounds__(448) void proj_lds(const unsigned int* __restrict__ Gq,
                                                float* __restrict__ S,
                                                float theta_step, float gmax,
                                                float gstep, float t0,
                                                float dtstep) {
    __shared__ unsigned int Lw[LWORDS];

    const int blk  = blockIdx.x;          // 0..5119
    const int a    = blk >> 4;
    const int tile = blk & 15;
    const int qi = tile >> 2, qj = tile & 3;
    const int r0 = 104 * qi - 2;          // first staged quad row
    const int c0 = 104 * qj - 2;          // first staged quad col

    // --- cooperative stage: 108 rows x 27 uint4 (16B-aligned both sides) ---
    {
        const uint4* __restrict__ src =
            (const uint4*)(Gq + (r0 + 2) * GQSTRIDE + (c0 + 2));
        for (int i = threadIdx.x; i < 108 * 27; i += 448) {
            int rr = i / 27, cc = i - rr * 27;
            uint4 w = src[rr * (GQSTRIDE / 4) + cc];
            *(uint4*)&Lw[rr * LSTRIDE + cc * 4] = w;
        }
    }
    __syncthreads();

    const int d = threadIdx.x;
    if (d < N_DET) {
        const float theta = (float)a * theta_step;
        const float gamma = fmaf((float)d, gstep, -gmax);
        float s1, c1, s2, c2;
        sincosf(theta, &s1, &c1);
        sincosf(theta + gamma, &s2, &c2);
        const float sx = fmaf(1075.0f, c1, 207.5f);
        const float sy = fmaf(1075.0f, s1, 207.5f);

        // col(k) = C0 - k*dc ; row(k) = R0 - k*dr   (k = 0..415)
        const float C0 = fmaf(-t0, c2, sx), dc = dtstep * c2;
        const float R0 = fmaf(-t0, s2, sy), dr = dtstep * s2;

        // tile ownership box, half-open [lo,hi). Edge tiles take the
        // out-of-image margin; beyond [-1,416) all taps are exactly zero.
        const float cl = (qj == 0) ? -1.0f : 104.0f * qj;
        const float ch = (qj == 3) ? 416.0f : 104.0f * (qj + 1);
        const float rl = (qi == 0) ? -1.0f : 104.0f * qi;
        const float rh = (qi == 3) ? 416.0f : 104.0f * (qi + 1);

        int klo = 0, khi = N_SAMP - 1;
        auto clip1 = [&](float X0, float dX, float lo, float hi) {
            if (fabsf(dX) < 1e-8f) {
                if (!(X0 >= lo && X0 < hi)) { klo = 1; khi = 0; }
            } else {
                const float inv = 1.0f / dX;
                float x1 = (X0 - hi) * inv;        // strict side
                float x2 = (X0 - lo) * inv;        // inclusive side
                x1 = fminf(fmaxf(x1, -1e6f), 1e6f);
                x2 = fminf(fmaxf(x2, -1e6f), 1e6f);
                int lo_k, hi_k;
                if (dX > 0.0f) { lo_k = (int)floorf(x1) + 1; hi_k = (int)floorf(x2); }
                else           { lo_k = (int)ceilf(x2);      hi_k = (int)ceilf(x1) - 1; }
                klo = max(klo, lo_k);
                khi = min(khi, hi_k);
            }
        };
        clip1(C0, dc, cl, ch);
        clip1(R0, dr, rl, rh);

        if (klo <= khi) {
            // tile-relative coords; inside the box colR,rowR >= 1 > 0, so
            // trunc == floor and taps land within the staged 108x108 region.
            float colR = fmaf(-(float)klo, dc, C0) - (float)c0;
            float rowR = fmaf(-(float)klo, dr, R0) - (float)r0;
            float acc = 0.0f;
            #pragma unroll 4
            for (int k = klo; k <= khi; ++k) {
                const int ci = (int)colR;
                const int ri = (int)rowR;
                const float wc = colR - (float)ci;
                const float wr = rowR - (float)ri;
                const unsigned int u = Lw[ri * LSTRIDE + ci];
                const vfloat2 lo2 = __builtin_amdgcn_cvt_pk_f32_fp8(u, false); // v00,v01
                const vfloat2 hi2 = __builtin_amdgcn_cvt_pk_f32_fp8(u, true);  // v10,v11
                const float top = fmaf(wc, lo2[1] - lo2[0], lo2[0]);
                const float bot = fmaf(wc, hi2[1] - hi2[0], hi2[0]);
                acc = fmaf(wr, bot - top, acc + top);
                colR -= dc;
                rowR -= dr;
            }
            atomicAdd(&S[a * N_DET + d], acc);
        }
    }
}

// ---------------------------------------------------------------------------
// Kernel C: square each ray integral, reduce, scale, one atomic per block.
// ---------------------------------------------------------------------------
__global__ __launch_bounds__(256) void reduce_kernel(const float* __restrict__ S,
                                                     float* __restrict__ out,
                                                     float coef) {
    const int i = blockIdx.x * 256 + threadIdx.x;
    float v = (i < SPLANE) ? S[i] : 0.0f;
    float sq = v * v;
    #pragma unroll
    for (int m = 32; m > 0; m >>= 1) sq += __shfl_down(sq, m, 64);
    __shared__ float w[4];
    const int lane = threadIdx.x & 63;
    if (lane == 0) w[threadIdx.x >> 6] = sq;
    __syncthreads();
    if (threadIdx.x == 0)
        atomicAdd(out, (w[0] + w[1] + w[2] + w[3]) * coef);
}

// ---------------------------------------------------------------------------
// Fallback (ws too small): fused one-thread-per-ray fp32 gather version.
// ---------------------------------------------------------------------------
__global__ __launch_bounds__(256) void proj_fused(const float* __restrict__ imgA,
                                                  const float* __restrict__ imgB,
                                                  float* __restrict__ out,
                                                  float theta_step, float gmax,
                                                  float gstep, float t0,
                                                  float dtstep, float coef) {
    const int idx = blockIdx.x * 256 + threadIdx.x;
    const int a  = idx / N_DET;
    const int dd = idx - a * N_DET;
    const float theta = (float)a * theta_step;
    const float gamma = fmaf((float)dd, gstep, -gmax);
    float s1, c1, s2, c2;
    sincosf(theta, &s1, &c1);
    sincosf(theta + gamma, &s2, &c2);
    const float sx = 1075.0f * c1 + 207.5f;
    const float sy = 1075.0f * s1 + 207.5f;
    float acc = 0.0f;
    #pragma unroll 4
    for (int s = 0; s < N_SAMP; ++s) {
        const float t   = fmaf((float)s, dtstep, t0);
        const float col = fmaf(-t, c2, sx);
        const float row = fmaf(-t, s2, sy);
        const float c0 = floorf(col);
        const float r0 = floorf(row);
        const float wc = col - c0;
        const float wr = row - r0;
        const int ci = (int)c0;
        const int ri = (int)r0;
        auto Gv = [&](int r, int c) -> float {
            if ((unsigned)r < (unsigned)IMG && (unsigned)c < (unsigned)IMG)
                return imgA[r * IMG + c] - imgB[r * IMG + c];
            return 0.0f;
        };
        const float v00 = Gv(ri, ci);
        const float v01 = Gv(ri, ci + 1);
        const float v10 = Gv(ri + 1, ci);
        const float v11 = Gv(ri + 1, ci + 1);
        const float top = fmaf(wc, v01 - v00, v00);
        const float bot = fmaf(wc, v11 - v10, v10);
        acc += fmaf(wr, bot - top, top);
    }
    float sq = acc * acc;
    #pragma unroll
    for (int o = 32; o > 0; o >>= 1) sq += __shfl_down(sq, o, 64);
    __shared__ float wsum[4];
    const int lane = threadIdx.x & 63;
    if (lane == 0) wsum[threadIdx.x >> 6] = sq;
    __syncthreads();
    if (threadIdx.x == 0)
        atomicAdd(out, (wsum[0] + wsum[1] + wsum[2] + wsum[3]) * coef);
}

extern "C" void kernel_launch(void* const* d_in, const int* in_sizes, int n_in,
                              void* d_out, int out_size, void* d_ws, size_t ws_size,
                              hipStream_t stream) {
    const float* in = (const float*)d_in[0];
    const float* tg = (const float*)d_in[1];
    float* out = (float*)d_out;

    const double half_diag = (IMG / 2.0) * sqrt(2.0);
    const double ray_len   = IMG * sqrt(2.0);
    const float  gmax      = (float)asin(half_diag / 1075.0);
    const float  gstep     = (float)(2.0 * (double)gmax / (N_DET - 1));
    const float  t0        = (float)(1075.0 - ray_len / 2.0);
    const float  dtstep    = (float)(ray_len / (N_SAMP - 1));
    const float  theta_step = (float)(2.0 * M_PI / N_ANG);
    const double dt        = ray_len / (N_SAMP - 1);
    const double SCALE     = 512.0 / 416.0 * 0.03;
    const float  coef      = (float)(dt * dt * SCALE / ((double)N_ANG * N_DET));

    if (ws_size >= WSNEED) {
        unsigned int* Gq = (unsigned int*)d_ws;
        float* S = (float*)((char*)d_ws + GQBYTES);
        pack_kernel<<<(GQWORDS + 255) / 256, 256, 0, stream>>>(in, tg, Gq, S, out);
        proj_lds<<<N_ANG * 16, 448, 0, stream>>>(Gq, S, theta_step, gmax, gstep,
                                                 t0, dtstep);
        reduce_kernel<<<(SPLANE + 255) / 256, 256, 0, stream>>>(S, out, coef);
    } else {
        zero_out_kernel<<<1, 64, 0, stream>>>(out);
        proj_fused<<<(N_ANG * N_DET) / 256, 256, 0, stream>>>(
            in, tg, out, theta_step, gmax, gstep, t0, dtstep, coef);
    }
}

// Round 10
// 110.536 us; speedup vs baseline: 1.1281x; 1.1281x over previous
//
#include <hip/hip_runtime.h>
#include <math.h>

#define IMG 416
#define N_ANG 320
#define N_DET 416
#define N_SAMP 416

// ---------------------------------------------------------------------------
// Padded global fp8 image G: stride 464 B, 432 rows. Pixel (r,c) of the diff
// image lives at G[(r+8)*464 + (c+8)], zero outside [0,416)^2.
// ---------------------------------------------------------------------------
#define GSTRIDE 464
#define GROWS   432
#define GBYTES  ((size_t)GROWS * GSTRIDE)        // 200448
#define GWORDS  (GROWS * GSTRIDE / 4)            // 50112

#define SPLANE  (N_ANG * N_DET)                  // 133120 rays
#define SBYTES  ((size_t)4 * SPLANE * sizeof(float))
#define WSNEED  (GBYTES + SBYTES)

// LDS staged quadrant: up to 229 rows x 59 dwords (236 B; 59%32=27, coprime
// with 32 banks). 229 rows = 227 needed + 2 GUARD rows: the incremental ray
// march drifts a few 1e-3 px past the clip box, so the bilinear can touch one
// row beyond it — guard rows keep those reads on staged (valid, zero-pad)
// data instead of stale LDS, which intermittently decoded to fp8-NaN (R9 bug).
#define LSTRIDE_W 59
#define LROWS     229
#define LWORDS    (LROWS * LSTRIDE_W)            // 13511 dwords = 54044 B -> 3 blk/CU

typedef float vfloat2 __attribute__((ext_vector_type(2)));

// ---------------------------------------------------------------------------
// Kernel A: build padded fp8 diff image (word-granular, fully overwrites G);
// zero d_out.
// ---------------------------------------------------------------------------
__global__ __launch_bounds__(256) void pack_kernel(const float* __restrict__ a,
                                                   const float* __restrict__ b,
                                                   unsigned int* __restrict__ G,
                                                   float* __restrict__ out) {
    int i = blockIdx.x * 256 + threadIdx.x;
    if (i == 0) out[0] = 0.0f;
    if (i >= GWORDS) return;
    int pr = i / (GSTRIDE / 4);            // 116 words per padded row
    int wc = i - pr * (GSTRIDE / 4);
    int r  = pr - 8;
    int c0 = wc * 4 - 8;
    float v[4];
    #pragma unroll
    for (int j = 0; j < 4; ++j) {
        int c = c0 + j;
        float val = 0.0f;
        if ((unsigned)r < (unsigned)IMG && (unsigned)c < (unsigned)IMG) {
            int idx = r * IMG + c;
            val = a[idx] - b[idx];
        }
        v[j] = val;
    }
    unsigned int u = __builtin_amdgcn_cvt_pk_fp8_f32(v[0], v[1], 0u, false);
    u = __builtin_amdgcn_cvt_pk_fp8_f32(v[2], v[3], u, true);
    G[i] = u;
}

__global__ void zero_out_kernel(float* __restrict__ out) {
    if (threadIdx.x == 0) out[0] = 0.0f;
}

// ---------------------------------------------------------------------------
// Kernel B: block = (angle, quadrant), thread = detector. Stage the quadrant
// (+2 guard rows) into LDS (1 B/px, 236 B stride), then march the ray's exact
// sample range inside the quadrant's half-open ownership box. Per sample:
// 2x ds_read2_b32 (row-pair dwords) + 64-bit funnel shift + 2x HW fp8 unpack.
// Partial ray sums -> 4 sinogram planes (no atomics).
// ---------------------------------------------------------------------------
__global__ __launch_bounds__(448) void proj_lds(const unsigned int* __restrict__ G,
                                                float* __restrict__ S,
                                                float theta_step, float gmax,
                                                float gstep, float t0,
                                                float dtstep) {
    __shared__ unsigned int Lw[LWORDS];

    const int blk = blockIdx.x;          // 0..1279
    const int a  = blk >> 2;
    const int q  = blk & 3;
    const int qi = q >> 1, qj = q & 1;
    const int r0 = qi ? 222 : -2;        // first staged pixel row
    const int c0 = qj ? 220 : -4;        // first staged pixel col
    const int nrows = (qi ? 197 : 227) + 2;   // +2 guard rows (valid G data)

    // --- cooperative stage: nrows x 59 dwords (word-aligned in G) ----------
    // Max G row touched: qi=0: 6+228=234; qi=1: 230+198=428  (< 432, valid).
    {
        const int gbase = ((r0 + 8) * GSTRIDE + (c0 + 8)) >> 2;  // word index
        const int total = nrows * LSTRIDE_W;
        for (int i = threadIdx.x; i < total; i += 448) {
            int rr = i / LSTRIDE_W;
            int cc = i - rr * LSTRIDE_W;
            Lw[rr * LSTRIDE_W + cc] = G[gbase + rr * 116 + cc];
        }
    }
    __syncthreads();

    const int d = threadIdx.x;
    if (d < N_DET) {
        const float theta = (float)a * theta_step;
        const float gamma = fmaf((float)d, gstep, -gmax);
        float s1, c1, s2, c2;
        sincosf(theta, &s1, &c1);
        sincosf(theta + gamma, &s2, &c2);
        const float sx = fmaf(1075.0f, c1, 207.5f);
        const float sy = fmaf(1075.0f, s1, 207.5f);

        // col(k) = C0 - k*dc ; row(k) = R0 - k*dr   (k = 0..415)
        const float C0 = fmaf(-t0, c2, sx), dc = dtstep * c2;
        const float R0 = fmaf(-t0, s2, sy), dr = dtstep * s2;

        // ownership box, half-open; support of nonzero taps is [-1,416).
        // Shared inner boundaries evaluate the same fp expression in both
        // neighboring quadrants -> exact partition of each ray's samples.
        const float cl = qj ? 224.0f : -1.0f, ch = qj ? 416.0f : 224.0f;
        const float rl = qi ? 224.0f : -1.0f, rh = qi ? 416.0f : 224.0f;

        int klo = 0, khi = N_SAMP - 1;
        auto clip1 = [&](float X0, float dX, float lo, float hi) {
            if (fabsf(dX) < 1e-8f) {
                if (!(X0 >= lo && X0 < hi)) { klo = 1; khi = 0; }
            } else {
                const float inv = 1.0f / dX;
                float x1 = (X0 - hi) * inv;        // strict side
                float x2 = (X0 - lo) * inv;        // inclusive side
                x1 = fminf(fmaxf(x1, -1e6f), 1e6f);
                x2 = fminf(fmaxf(x2, -1e6f), 1e6f);
                int lo_k, hi_k;
                if (dX > 0.0f) { lo_k = (int)floorf(x1) + 1; hi_k = (int)floorf(x2); }
                else           { lo_k = (int)ceilf(x2);      hi_k = (int)ceilf(x1) - 1; }
                klo = max(klo, lo_k);
                khi = min(khi, hi_k);
            }
        };
        clip1(C0, dc, cl, ch);
        clip1(R0, dr, rl, rh);

        float acc = 0.0f;
        if (klo <= khi) {
            // LDS-relative coords (>=1 inside the box -> trunc==floor; march
            // drift is <1e-2 px, absorbed by the guard rows / column slack)
            float colR = fmaf(-(float)klo, dc, C0) - (float)c0;
            float rowR = fmaf(-(float)klo, dr, R0) - (float)r0;
            #pragma unroll 4
            for (int k = klo; k <= khi; ++k) {
                const int ci = (int)colR;
                const int ri = (int)rowR;
                const float wc = colR - (float)ci;
                const float wr = rowR - (float)ri;
                const int widx = ri * LSTRIDE_W + (ci >> 2);
                // two ds_read2_b32: {w, w+59} and {w+1, w+60}
                const unsigned int d00 = Lw[widx];
                const unsigned int d10 = Lw[widx + LSTRIDE_W];
                const unsigned int d01 = Lw[widx + 1];
                const unsigned int d11 = Lw[widx + LSTRIDE_W + 1];
                const int sh8 = (ci & 3) << 3;
                const unsigned int r0w =
                    (unsigned int)(((((unsigned long long)d01) << 32) | d00) >> sh8);
                const unsigned int r1w =
                    (unsigned int)(((((unsigned long long)d11) << 32) | d10) >> sh8);
                const vfloat2 t2 = __builtin_amdgcn_cvt_pk_f32_fp8(r0w, false); // v00,v01
                const vfloat2 b2 = __builtin_amdgcn_cvt_pk_f32_fp8(r1w, false); // v10,v11
                const float top = fmaf(wc, t2[1] - t2[0], t2[0]);
                const float bot = fmaf(wc, b2[1] - b2[0], b2[0]);
                acc = fmaf(wr, bot - top, acc + top);
                colR -= dc;
                rowR -= dr;
            }
        }
        S[q * SPLANE + a * N_DET + d] = acc;
    }
}

// ---------------------------------------------------------------------------
// Kernel C: combine the 4 quadrant partials per ray, square, reduce, scale.
// ---------------------------------------------------------------------------
__global__ __launch_bounds__(256) void reduce_kernel(const float* __restrict__ S,
                                                     float* __restrict__ out,
                                                     float coef) {
    const int i = blockIdx.x * 256 + threadIdx.x;
    float v = 0.0f;
    if (i < SPLANE)
        v = (S[i] + S[SPLANE + i]) + (S[2 * SPLANE + i] + S[3 * SPLANE + i]);
    float sq = v * v;
    #pragma unroll
    for (int m = 32; m > 0; m >>= 1) sq += __shfl_down(sq, m, 64);
    __shared__ float w[4];
    const int lane = threadIdx.x & 63;
    if (lane == 0) w[threadIdx.x >> 6] = sq;
    __syncthreads();
    if (threadIdx.x == 0)
        atomicAdd(out, (w[0] + w[1] + w[2] + w[3]) * coef);
}

// ---------------------------------------------------------------------------
// Fallback (ws too small): fused one-thread-per-ray fp32 gather version.
// ---------------------------------------------------------------------------
__global__ __launch_bounds__(256) void proj_fused(const float* __restrict__ imgA,
                                                  const float* __restrict__ imgB,
                                                  float* __restrict__ out,
                                                  float theta_step, float gmax,
                                                  float gstep, float t0,
                                                  float dtstep, float coef) {
    const int idx = blockIdx.x * 256 + threadIdx.x;
    const int a  = idx / N_DET;
    const int dd = idx - a * N_DET;
    const float theta = (float)a * theta_step;
    const float gamma = fmaf((float)dd, gstep, -gmax);
    float s1, c1, s2, c2;
    sincosf(theta, &s1, &c1);
    sincosf(theta + gamma, &s2, &c2);
    const float sx = 1075.0f * c1 + 207.5f;
    const float sy = 1075.0f * s1 + 207.5f;
    float acc = 0.0f;
    #pragma unroll 4
    for (int s = 0; s < N_SAMP; ++s) {
        const float t   = fmaf((float)s, dtstep, t0);
        const float col = fmaf(-t, c2, sx);
        const float row = fmaf(-t, s2, sy);
        const float c0 = floorf(col);
        const float r0 = floorf(row);
        const float wc = col - c0;
        const float wr = row - r0;
        const int ci = (int)c0;
        const int ri = (int)r0;
        auto Gv = [&](int r, int c) -> float {
            if ((unsigned)r < (unsigned)IMG && (unsigned)c < (unsigned)IMG)
                return imgA[r * IMG + c] - imgB[r * IMG + c];
            return 0.0f;
        };
        const float v00 = Gv(ri, ci);
        const float v01 = Gv(ri, ci + 1);
        const float v10 = Gv(ri + 1, ci);
        const float v11 = Gv(ri + 1, ci + 1);
        const float top = fmaf(wc, v01 - v00, v00);
        const float bot = fmaf(wc, v11 - v10, v10);
        acc += fmaf(wr, bot - top, top);
    }
    float sq = acc * acc;
    #pragma unroll
    for (int o = 32; o > 0; o >>= 1) sq += __shfl_down(sq, o, 64);
    __shared__ float wsum[4];
    const int lane = threadIdx.x & 63;
    if (lane == 0) wsum[threadIdx.x >> 6] = sq;
    __syncthreads();
    if (threadIdx.x == 0)
        atomicAdd(out, (wsum[0] + wsum[1] + wsum[2] + wsum[3]) * coef);
}

extern "C" void kernel_launch(void* const* d_in, const int* in_sizes, int n_in,
                              void* d_out, int out_size, void* d_ws, size_t ws_size,
                              hipStream_t stream) {
    const float* in = (const float*)d_in[0];
    const float* tg = (const float*)d_in[1];
    float* out = (float*)d_out;

    const double half_diag = (IMG / 2.0) * sqrt(2.0);
    const double ray_len   = IMG * sqrt(2.0);
    const float  gmax      = (float)asin(half_diag / 1075.0);
    const float  gstep     = (float)(2.0 * (double)gmax / (N_DET - 1));
    const float  t0        = (float)(1075.0 - ray_len / 2.0);
    const float  dtstep    = (float)(ray_len / (N_SAMP - 1));
    const float  theta_step = (float)(2.0 * M_PI / N_ANG);
    const double dt        = ray_len / (N_SAMP - 1);
    const double SCALE     = 512.0 / 416.0 * 0.03;
    const float  coef      = (float)(dt * dt * SCALE / ((double)N_ANG * N_DET));

    if (ws_size >= WSNEED) {
        unsigned int* G = (unsigned int*)d_ws;
        float* S = (float*)((char*)d_ws + GBYTES);
        pack_kernel<<<(GWORDS + 255) / 256, 256, 0, stream>>>(in, tg, G, out);
        proj_lds<<<N_ANG * 4, 448, 0, stream>>>(G, S, theta_step, gmax, gstep,
                                                t0, dtstep);
        reduce_kernel<<<(SPLANE + 255) / 256, 256, 0, stream>>>(S, out, coef);
    } else {
        zero_out_kernel<<<1, 64, 0, stream>>>(out);
        proj_fused<<<(N_ANG * N_DET) / 256, 256, 0, stream>>>(
            in, tg, out, theta_step, gmax, gstep, t0, dtstep, coef);
    }
}